// Round 2
// baseline (334.237 us; speedup 1.0000x reference)
//
#include <hip/hip_runtime.h>

typedef unsigned short u16;
typedef __attribute__((ext_vector_type(8))) short bfrag;  // 8 bf16 = 4 VGPRs (MFMA A/B frag)
typedef __attribute__((ext_vector_type(4))) float ffrag;  // 4 fp32 (MFMA C/D frag)

// B=256, L=200, D=256, H=16, Dh=16, M=B*L=51200
// Inputs are FLOAT32 (per reference dtypes); mask int32; output float32.
// Internal intermediates (Q/K/V/ctx/news_out, weights) are bf16 — the test
// threshold is 2% of output absmax, bf16 rounding is ~0.2% relative.

__device__ __forceinline__ float bf2f(u16 u) {
    union { float f; unsigned int i; } c; c.i = ((unsigned int)u) << 16; return c.f;
}
__device__ __forceinline__ u16 f2bf(float f) {
    union { float f; unsigned int i; } c; c.f = f;
    unsigned int r = c.i + 0x7FFFu + ((c.i >> 16) & 1u);  // RNE
    return (u16)(r >> 16);
}
__device__ __forceinline__ ffrag mfma16(bfrag a, bfrag b, ffrag c) {
    return __builtin_amdgcn_mfma_f32_16x16x32_bf16(a, b, c, 0, 0, 0);
}

// ---------------------------------------------------------------------------
// Transpose+cast the 4 f32 weight matrices [256,256] -> bf16 Wt[n][k]
// ---------------------------------------------------------------------------
__global__ __launch_bounds__(256) void transpose_k(
    const float* __restrict__ W0, const float* __restrict__ W1,
    const float* __restrict__ W2, const float* __restrict__ W3,
    u16* __restrict__ Wt)
{
    const float* W = (blockIdx.y == 0) ? W0 : (blockIdx.y == 1) ? W1
                   : (blockIdx.y == 2) ? W2 : W3;
    int k = blockIdx.x, n = threadIdx.x;
    Wt[(size_t)blockIdx.y * 65536 + (size_t)n * 256 + k] = f2bf(W[(size_t)k * 256 + n]);
}

// ---------------------------------------------------------------------------
// C[M,256] = A[M,256] @ W[256,256] + bias   (W transposed bf16: Wt[n][k])
// A is f32 (AF32=true) or bf16 (AF32=false). C written bf16.
// block tile 128x128, wave tile 64x64, BK=32, XOR-swizzled LDS
// grid (400, 2)
// ---------------------------------------------------------------------------
template<bool AF32>
__global__ __launch_bounds__(256) void gemm_t(
    const void* __restrict__ Avp, const u16* __restrict__ Wt,
    const float* __restrict__ bias, u16* __restrict__ C)
{
    const int m0 = blockIdx.x * 128;
    const int n0 = blockIdx.y * 128;
    const int tid = threadIdx.x;
    const int wave = tid >> 6, lane = tid & 63;
    const int quad = lane >> 4, l16 = lane & 15;
    const int wm = wave >> 1, wn = wave & 1;

    __shared__ u16 a_s[4][128][8];   // [k-chunk][row(xor-swizzled)][8 elems]
    __shared__ u16 b_s[4][128][8];

    ffrag zf = {0.f, 0.f, 0.f, 0.f};
    ffrag acc[4][4];
#pragma unroll
    for (int mi = 0; mi < 4; mi++)
#pragma unroll
        for (int ni = 0; ni < 4; ni++) acc[mi][ni] = zf;

    const int sr = tid >> 2;     // 0..63
    const int sc = tid & 3;      // k-chunk 0..3
    const float* Af = (const float*)Avp;
    const u16*   Ab = (const u16*)Avp;
    const u16* Wp = Wt + (size_t)(n0 + sr) * 256 + sc * 8;

    for (int kk = 0; kk < 256; kk += 32) {
        __syncthreads();
        if constexpr (AF32) {
            const float* p0 = Af + (size_t)(m0 + sr) * 256 + sc * 8 + kk;
            const float* p1 = p0 + (size_t)64 * 256;
            float4 f0 = *(const float4*)p0, f1 = *(const float4*)(p0 + 4);
            float4 g0 = *(const float4*)p1, g1 = *(const float4*)(p1 + 4);
            bfrag v0, v1;
            v0[0] = (short)f2bf(f0.x); v0[1] = (short)f2bf(f0.y);
            v0[2] = (short)f2bf(f0.z); v0[3] = (short)f2bf(f0.w);
            v0[4] = (short)f2bf(f1.x); v0[5] = (short)f2bf(f1.y);
            v0[6] = (short)f2bf(f1.z); v0[7] = (short)f2bf(f1.w);
            v1[0] = (short)f2bf(g0.x); v1[1] = (short)f2bf(g0.y);
            v1[2] = (short)f2bf(g0.z); v1[3] = (short)f2bf(g0.w);
            v1[4] = (short)f2bf(g1.x); v1[5] = (short)f2bf(g1.y);
            v1[6] = (short)f2bf(g1.z); v1[7] = (short)f2bf(g1.w);
            *(bfrag*)&a_s[sc][sr        ^ (sc << 2)][0] = v0;
            *(bfrag*)&a_s[sc][(sr + 64) ^ (sc << 2)][0] = v1;
        } else {
            const u16* p0 = Ab + (size_t)(m0 + sr) * 256 + sc * 8 + kk;
            *(bfrag*)&a_s[sc][sr        ^ (sc << 2)][0] = *(const bfrag*)p0;
            *(bfrag*)&a_s[sc][(sr + 64) ^ (sc << 2)][0] = *(const bfrag*)(p0 + (size_t)64 * 256);
        }
        *(bfrag*)&b_s[sc][sr        ^ (sc << 2)][0] = *(const bfrag*)(Wp + kk);
        *(bfrag*)&b_s[sc][(sr + 64) ^ (sc << 2)][0] = *(const bfrag*)(Wp + (size_t)64 * 256 + kk);
        __syncthreads();

        bfrag af[4], bfr[4];
#pragma unroll
        for (int mi = 0; mi < 4; mi++) {
            int m = wm * 64 + mi * 16 + l16;
            af[mi] = *(const bfrag*)&a_s[quad][m ^ (quad << 2)][0];
        }
#pragma unroll
        for (int ni = 0; ni < 4; ni++) {
            int n = wn * 64 + ni * 16 + l16;
            bfr[ni] = *(const bfrag*)&b_s[quad][n ^ (quad << 2)][0];
        }
#pragma unroll
        for (int mi = 0; mi < 4; mi++)
#pragma unroll
            for (int ni = 0; ni < 4; ni++)
                acc[mi][ni] = mfma16(af[mi], bfr[ni], acc[mi][ni]);
    }

#pragma unroll
    for (int ni = 0; ni < 4; ni++) {
        int col = n0 + wn * 64 + ni * 16 + l16;
        float bb = bias[col];
#pragma unroll
        for (int mi = 0; mi < 4; mi++) {
            int rowb = m0 + wm * 64 + mi * 16 + quad * 4;
#pragma unroll
            for (int r = 0; r < 4; r++)
                C[(size_t)(rowb + r) * 256 + col] = f2bf(acc[mi][ni][r] + bb);
        }
    }
}

// ---------------------------------------------------------------------------
// MHA per (b,h). grid = B*H = 4096, block = 256 (4 waves). bf16 in/out.
// Writes ctx in-place over the Q buffer (each block owns its (b,h) slice).
// ---------------------------------------------------------------------------
__global__ __launch_bounds__(256) void attn_k(
    const u16* __restrict__ Q, const u16* __restrict__ K,
    const u16* __restrict__ V, const int* __restrict__ msk,
    u16* __restrict__ Ctx)
{
    const int b = blockIdx.x >> 4;
    const int h = blockIdx.x & 15;
    const int tid = threadIdx.x;
    const int wave = tid >> 6, lane = tid & 63;
    const int quad = lane >> 4, l16 = lane & 15;

    __shared__ u16 q_s[208][24];       // rows padded to 208, pitch 24
    __shared__ u16 k_s[208][24];
    __shared__ u16 vt_s[16][232];      // V transposed [dh][l]
    __shared__ u16 p_s[4][16][232];    // per-wave P tile [q][k]
    __shared__ float am_s[224];        // additive key mask

    bfrag z8 = {0, 0, 0, 0, 0, 0, 0, 0};

    for (int i = tid; i < 224; i += 256)
        am_s[i] = (i < 200) ? (msk[b * 200 + i] ? 0.f : -10000.f) : -1e30f;
    for (int i = tid; i < 16 * 32; i += 256)
        vt_s[i >> 5][200 + (i & 31)] = 0;
    for (int i = tid; i < 4 * 16 * 16; i += 256)
        p_s[i >> 8][(i & 255) >> 4][208 + (i & 15)] = 0;

    for (int i = tid; i < 416; i += 256) {          // Q rows
        int l = i >> 1, hf = i & 1;
        bfrag v = z8;
        if (l < 200) v = *(const bfrag*)(Q + (size_t)(b * 200 + l) * 256 + h * 16 + hf * 8);
        *(bfrag*)&q_s[l][hf * 8] = v;
    }
    for (int i = tid; i < 416; i += 256) {          // K rows
        int l = i >> 1, hf = i & 1;
        bfrag v = z8;
        if (l < 200) v = *(const bfrag*)(K + (size_t)(b * 200 + l) * 256 + h * 16 + hf * 8);
        *(bfrag*)&k_s[l][hf * 8] = v;
    }
    for (int i = tid; i < 400; i += 256) {          // V rows -> transposed
        int l = i >> 1, hf = i & 1;
        bfrag v = *(const bfrag*)(V + (size_t)(b * 200 + l) * 256 + h * 16 + hf * 8);
#pragma unroll
        for (int j = 0; j < 8; j++) vt_s[hf * 8 + j][l] = (u16)v[j];
    }
    __syncthreads();

    for (int t = wave; t < 13; t += 4) {
        int qb = t * 16;
        // ---- scores: S[16 q][208 k], Dh=16 padded to K=32 (quads 2,3 zero)
        bfrag aq = z8;
        if (quad < 2) aq = *(const bfrag*)&q_s[qb + l16][quad * 8];
        float s[13][4];
#pragma unroll
        for (int kt = 0; kt < 13; kt++) {
            bfrag bk8 = z8;
            if (quad < 2) bk8 = *(const bfrag*)&k_s[kt * 16 + l16][quad * 8];
            ffrag c = {0.f, 0.f, 0.f, 0.f};
            c = mfma16(aq, bk8, c);
            float am = am_s[kt * 16 + l16];
#pragma unroll
            for (int r = 0; r < 4; r++) s[kt][r] = c[r] * 0.25f + am;
        }
        // ---- softmax over k (row = quad*4+r lives in this quad's 16 lanes)
        float mx[4], sm[4];
#pragma unroll
        for (int r = 0; r < 4; r++) {
            mx[r] = s[0][r];
#pragma unroll
            for (int kt = 1; kt < 13; kt++) mx[r] = fmaxf(mx[r], s[kt][r]);
#pragma unroll
            for (int d = 1; d < 16; d <<= 1) mx[r] = fmaxf(mx[r], __shfl_xor(mx[r], d, 64));
            sm[r] = 0.f;
        }
#pragma unroll
        for (int kt = 0; kt < 13; kt++)
#pragma unroll
            for (int r = 0; r < 4; r++) {
                float p = __expf(s[kt][r] - mx[r]);
                s[kt][r] = p; sm[r] += p;
            }
#pragma unroll
        for (int r = 0; r < 4; r++)
#pragma unroll
            for (int d = 1; d < 16; d <<= 1) sm[r] += __shfl_xor(sm[r], d, 64);
        // ---- P (C-layout) -> LDS (A-layout source), bf16
#pragma unroll
        for (int kt = 0; kt < 13; kt++)
#pragma unroll
            for (int r = 0; r < 4; r++)
                p_s[wave][quad * 4 + r][kt * 16 + l16] = f2bf(s[kt][r]);
        // ---- PV: [16 q][224 k] @ [224 k][16 dh]
        ffrag o = {0.f, 0.f, 0.f, 0.f};
#pragma unroll
        for (int kc = 0; kc < 7; kc++) {
            bfrag ap  = *(const bfrag*)&p_s[wave][l16][kc * 32 + quad * 8];
            bfrag bv8 = *(const bfrag*)&vt_s[l16][kc * 32 + quad * 8];
            o = mfma16(ap, bv8, o);
        }
#pragma unroll
        for (int r = 0; r < 4; r++) {
            int l = qb + quad * 4 + r;
            if (l < 200)
                Ctx[(size_t)(b * 200 + l) * 256 + h * 16 + l16] = f2bf(o[r] / sm[r]);
        }
    }
}

// ---------------------------------------------------------------------------
// Query pooling per batch. grid = 256, block = 256. f32 out.
// ---------------------------------------------------------------------------
__global__ __launch_bounds__(256) void pool_k(
    const u16* __restrict__ NO, const int* __restrict__ msk,
    const float* __restrict__ qn, float* __restrict__ out)
{
    const int b = blockIdx.x;
    const int tid = threadIdx.x;
    __shared__ float q_sh[256];
    __shared__ float p_sh[256];
    __shared__ float redm[4], reds[4];

    q_sh[tid] = qn[tid];
    __syncthreads();

    float s = -1e30f;
    if (tid < 200) {
        const u16* row = NO + (size_t)(b * 200 + tid) * 256;
        float acc = 0.f;
        for (int d0 = 0; d0 < 256; d0 += 8) {
            bfrag v = *(const bfrag*)(row + d0);
#pragma unroll
            for (int j = 0; j < 8; j++) acc += bf2f((u16)v[j]) * q_sh[d0 + j];
        }
        s = acc * 0.0625f;                       // 1/sqrt(256)
        if (msk[b * 200 + tid] == 0) s = -1e9f;  // matches reference where()
    }
    float m = s;
#pragma unroll
    for (int d = 1; d < 64; d <<= 1) m = fmaxf(m, __shfl_xor(m, d, 64));
    if ((tid & 63) == 0) redm[tid >> 6] = m;
    __syncthreads();
    m = fmaxf(fmaxf(redm[0], redm[1]), fmaxf(redm[2], redm[3]));
    float e = __expf(s - m);
    float sum = e;
#pragma unroll
    for (int d = 1; d < 64; d <<= 1) sum += __shfl_xor(sum, d, 64);
    if ((tid & 63) == 0) reds[tid >> 6] = sum;
    __syncthreads();
    sum = reds[0] + reds[1] + reds[2] + reds[3];
    p_sh[tid] = e / sum;
    __syncthreads();

    float acc = 0.f;
    for (int l = 0; l < 200; l++)
        acc += p_sh[l] * bf2f(NO[(size_t)(b * 200 + l) * 256 + tid]);
    out[(size_t)b * 256 + tid] = acc;
}

// ---------------------------------------------------------------------------
extern "C" void kernel_launch(void* const* d_in, const int* in_sizes, int n_in,
                              void* d_out, int out_size, void* d_ws, size_t ws_size,
                              hipStream_t stream) {
    const float* X   = (const float*)d_in[0];
    const int*   msk = (const int*)d_in[1];
    const float* Wq  = (const float*)d_in[2];
    const float* bq  = (const float*)d_in[3];
    const float* Wk  = (const float*)d_in[4];
    const float* bk  = (const float*)d_in[5];
    const float* Wv  = (const float*)d_in[6];
    const float* bv  = (const float*)d_in[7];
    const float* Wo  = (const float*)d_in[8];
    const float* bo  = (const float*)d_in[9];
    const float* qn  = (const float*)d_in[10];
    float* out = (float*)d_out;

    // ws layout (needs 79,167,488 B):
    //   qbuf (Q bf16, then ctx in-place) : 26,214,400
    //   kbuf (K bf16, then news_out)     : 26,214,400
    //   vbuf (V bf16)                    : 26,214,400
    //   wt   (4x transposed bf16 weights):    524,288
    char* ws = (char*)d_ws;
    u16* qbuf = (u16*)(ws);
    u16* kbuf = (u16*)(ws + 26214400);
    u16* vbuf = (u16*)(ws + 52428800);
    u16* wt   = (u16*)(ws + 78643200);

    transpose_k<<<dim3(256, 4), 256, 0, stream>>>(Wq, Wk, Wv, Wo, wt);

    dim3 gg(400, 2);
    gemm_t<true><<<gg, 256, 0, stream>>>(X, wt,          bq, qbuf);
    gemm_t<true><<<gg, 256, 0, stream>>>(X, wt + 65536,  bk, kbuf);
    gemm_t<true><<<gg, 256, 0, stream>>>(X, wt + 131072, bv, vbuf);

    attn_k<<<4096, 256, 0, stream>>>(qbuf, kbuf, vbuf, msk, qbuf);

    gemm_t<false><<<gg, 256, 0, stream>>>(qbuf, wt + 196608, bo, kbuf);  // news_out

    pool_k<<<256, 256, 0, stream>>>(kbuf, msk, qn, out);
}

// Round 4
// 312.946 us; speedup vs baseline: 1.0680x; 1.0680x over previous
//
#include <hip/hip_runtime.h>

typedef unsigned short u16;
typedef __attribute__((ext_vector_type(8))) short bfrag;  // 8 bf16 (4 VGPRs)
typedef __attribute__((ext_vector_type(4))) float ffrag;  // 4 fp32

// B=256, L=200, D=256, H=16, Dh=16, M=51200
// Head-major slice: [B,H,L,16], slice stride 3200 u16, b-stride 51200 u16.

__device__ __forceinline__ float bf2f(u16 u) {
    union { float f; unsigned int i; } c; c.i = ((unsigned int)u) << 16; return c.f;
}
__device__ __forceinline__ u16 f2bf(float f) {
    union { float f; unsigned int i; } c; c.f = f;
    unsigned int r = c.i + 0x7FFFu + ((c.i >> 16) & 1u);  // RNE
    return (u16)(r >> 16);
}
__device__ __forceinline__ ffrag mfma16(bfrag a, bfrag b, ffrag c) {
    return __builtin_amdgcn_mfma_f32_16x16x32_bf16(a, b, c, 0, 0, 0);
}

// ---------------------------------------------------------------------------
// LDS-tiled transpose+cast: W[k][n] f32 -> Wt[n][k] bf16, 4 matrices.
// grid (4 k-tiles, 4 n-tiles, 4 mats), block 256.
// Each thread stages 16 elems and writes BOTH 8-elem halves back.
// ---------------------------------------------------------------------------
__global__ __launch_bounds__(256) void wtrans_k(
    const float* __restrict__ W0, const float* __restrict__ W1,
    const float* __restrict__ W2, const float* __restrict__ W3,
    u16* __restrict__ Wt)
{
    __shared__ u16 t_s[64][72];
    const int mat = blockIdx.z;
    const float* W = (mat == 0) ? W0 : (mat == 1) ? W1 : (mat == 2) ? W2 : W3;
    const int k0 = blockIdx.x * 64, n0 = blockIdx.y * 64;
    const int r = threadIdx.x >> 2, cq = threadIdx.x & 3;

    const float* src = W + (size_t)(k0 + r) * 256 + n0 + cq * 16;
#pragma unroll
    for (int j = 0; j < 16; j += 4) {
        float4 f = *(const float4*)(src + j);
        t_s[cq * 16 + j + 0][r] = f2bf(f.x);
        t_s[cq * 16 + j + 1][r] = f2bf(f.y);
        t_s[cq * 16 + j + 2][r] = f2bf(f.z);
        t_s[cq * 16 + j + 3][r] = f2bf(f.w);
    }
    __syncthreads();
    u16* dst = Wt + ((size_t)mat * 256 + n0 + r) * 256 + k0 + cq * 16;
    *(bfrag*)(dst)     = *(const bfrag*)&t_s[r][cq * 16];
    *(bfrag*)(dst + 8) = *(const bfrag*)&t_s[r][cq * 16 + 8];
}

// ---------------------------------------------------------------------------
// GEMM: C[M,256or768] = A[M,256] @ Wt^T + bias.
// QKV=true : A = X (f32, l-major), grid (400,6), writes Q/K/V head-major bf16.
// QKV=false: A = ctx (bf16, head-major), grid (400,2), writes l-major bf16.
// block tile 128x128, wave tile 64x64, BK=32, XOR-swizzled LDS.
// ---------------------------------------------------------------------------
template<bool QKV>
__global__ __launch_bounds__(256) void gemm_k(
    const void* __restrict__ Avp, const u16* __restrict__ Wtp,
    const float* __restrict__ b0, const float* __restrict__ b1,
    const float* __restrict__ b2,
    u16* __restrict__ o0, u16* __restrict__ o1, u16* __restrict__ o2)
{
    const int m0 = blockIdx.x * 128;
    const int n0g = blockIdx.y * 128;
    const int tid = threadIdx.x;
    const int wave = tid >> 6, lane = tid & 63;
    const int quad = lane >> 4, l16 = lane & 15;
    const int wm = wave >> 1, wn = wave & 1;

    __shared__ u16 a_s[4][128][8];
    __shared__ u16 b_s[4][128][8];

    ffrag zf = {0.f, 0.f, 0.f, 0.f};
    ffrag acc[4][4];
#pragma unroll
    for (int mi = 0; mi < 4; mi++)
#pragma unroll
        for (int ni = 0; ni < 4; ni++) acc[mi][ni] = zf;

    const int sr = tid >> 2;     // 0..63
    const int sc = tid & 3;      // k-chunk 0..3
    const float* Af = (const float*)Avp;
    const u16*   Ab = (const u16*)Avp;
    const u16* Wp = Wtp + (size_t)(n0g + sr) * 256 + sc * 8;

    // head-major base for ctx rows (QKV=false)
    int r0 = m0 + sr, r1 = r0 + 64;
    unsigned bA0 = (unsigned)r0 / 200u, bA1 = (unsigned)r1 / 200u;
    size_t base0 = (size_t)bA0 * 51200 + (r0 - bA0 * 200) * 16;
    size_t base1 = (size_t)bA1 * 51200 + (r1 - bA1 * 200) * 16;

    for (int kk = 0; kk < 256; kk += 32) {
        __syncthreads();
        if constexpr (QKV) {
            const float* p0 = Af + (size_t)r0 * 256 + sc * 8 + kk;
            const float* p1 = Af + (size_t)r1 * 256 + sc * 8 + kk;
            float4 f0 = *(const float4*)p0, f1 = *(const float4*)(p0 + 4);
            float4 g0 = *(const float4*)p1, g1 = *(const float4*)(p1 + 4);
            bfrag v0, v1;
            v0[0] = (short)f2bf(f0.x); v0[1] = (short)f2bf(f0.y);
            v0[2] = (short)f2bf(f0.z); v0[3] = (short)f2bf(f0.w);
            v0[4] = (short)f2bf(f1.x); v0[5] = (short)f2bf(f1.y);
            v0[6] = (short)f2bf(f1.z); v0[7] = (short)f2bf(f1.w);
            v1[0] = (short)f2bf(g0.x); v1[1] = (short)f2bf(g0.y);
            v1[2] = (short)f2bf(g0.z); v1[3] = (short)f2bf(g0.w);
            v1[4] = (short)f2bf(g1.x); v1[5] = (short)f2bf(g1.y);
            v1[6] = (short)f2bf(g1.z); v1[7] = (short)f2bf(g1.w);
            *(bfrag*)&a_s[sc][sr        ^ (sc << 2)][0] = v0;
            *(bfrag*)&a_s[sc][(sr + 64) ^ (sc << 2)][0] = v1;
        } else {
            int c = kk + sc * 8;                    // channel, c&15 in {0,8}
            size_t hofs = (size_t)(c >> 4) * 3200 + (c & 8);
            *(bfrag*)&a_s[sc][sr        ^ (sc << 2)][0] = *(const bfrag*)(Ab + base0 + hofs);
            *(bfrag*)&a_s[sc][(sr + 64) ^ (sc << 2)][0] = *(const bfrag*)(Ab + base1 + hofs);
        }
        *(bfrag*)&b_s[sc][sr        ^ (sc << 2)][0] = *(const bfrag*)(Wp + kk);
        *(bfrag*)&b_s[sc][(sr + 64) ^ (sc << 2)][0] = *(const bfrag*)(Wp + (size_t)64 * 256 + kk);
        __syncthreads();

        bfrag af[4], bfr[4];
#pragma unroll
        for (int mi = 0; mi < 4; mi++) {
            int m = wm * 64 + mi * 16 + l16;
            af[mi] = *(const bfrag*)&a_s[quad][m ^ (quad << 2)][0];
        }
#pragma unroll
        for (int ni = 0; ni < 4; ni++) {
            int n = wn * 64 + ni * 16 + l16;
            bfr[ni] = *(const bfrag*)&b_s[quad][n ^ (quad << 2)][0];
        }
#pragma unroll
        for (int mi = 0; mi < 4; mi++)
#pragma unroll
            for (int ni = 0; ni < 4; ni++)
                acc[mi][ni] = mfma16(af[mi], bfr[ni], acc[mi][ni]);
    }

    if constexpr (QKV) {
        const float* bias = (blockIdx.y < 2) ? b0 : (blockIdx.y < 4) ? b1 : b2;
        u16* dst = (blockIdx.y < 2) ? o0 : (blockIdx.y < 4) ? o1 : o2;
#pragma unroll
        for (int ni = 0; ni < 4; ni++) {
            int nloc = (blockIdx.y & 1) * 128 + wn * 64 + ni * 16 + l16;  // 0..255
            float bb = bias[nloc];
            size_t hbase = (size_t)(nloc >> 4) * 3200 + (nloc & 15);
#pragma unroll
            for (int mi = 0; mi < 4; mi++) {
                int rowb = m0 + wm * 64 + mi * 16 + quad * 4;
#pragma unroll
                for (int r = 0; r < 4; r++) {
                    unsigned row = rowb + r;
                    unsigned bb_ = row / 200u, ll = row - bb_ * 200u;
                    dst[(size_t)bb_ * 51200 + hbase + ll * 16] = f2bf(acc[mi][ni][r] + bb);
                }
            }
        }
    } else {
#pragma unroll
        for (int ni = 0; ni < 4; ni++) {
            int col = n0g + wn * 64 + ni * 16 + l16;
            float bb = b0[col];
#pragma unroll
            for (int mi = 0; mi < 4; mi++) {
                int rowb = m0 + wm * 64 + mi * 16 + quad * 4;
#pragma unroll
                for (int r = 0; r < 4; r++)
                    o0[(size_t)(rowb + r) * 256 + col] = f2bf(acc[mi][ni][r] + bb);
            }
        }
    }
}

// ---------------------------------------------------------------------------
// MHA per (b,h). grid 4096, block 256 (4 waves). Head-major bf16 Q/K/V.
// Q/K fragments read DIRECTLY from global (L2-resident 6.4 KB slices).
// ctx written IN-PLACE over Q (per-wave: tile-t reads precede tile-t writes).
// p_s swizzle convention (store == read == zero-fill): element (row, col)
// lives at chunk (col>>3) ^ (row&3), i.e. byte col ((ch<<3)|(col&7)).
// ---------------------------------------------------------------------------
__global__ __launch_bounds__(256) void attn_k(
    u16* __restrict__ Q, const u16* __restrict__ K,
    const u16* __restrict__ V, const int* __restrict__ msk)
{
    const int blk = blockIdx.x;            // b*16+h
    const int b = blk >> 4;
    const int tid = threadIdx.x;
    const int wave = tid >> 6, lane = tid & 63;
    const int quad = lane >> 4, l16 = lane & 15;
    const size_t sbase = (size_t)blk * 3200;

    __shared__ u16 vt_s[16][232];          // V^T [dh][l], pitch 232 (16B-mult)
    __shared__ u16 p_s[4][16][232];        // per-wave P, chunk-swizzled
    __shared__ float am_s[224];

    for (int i = tid; i < 224; i += 256)
        am_s[i] = (i < 200) ? (msk[b * 200 + i] ? 0.f : -10000.f) : -1e30f;
    for (int i = tid; i < 16 * 32; i += 256)
        vt_s[i >> 5][200 + (i & 31)] = 0;
    // zero logical P cols 200..223 (same swizzle convention as store/read)
    for (int i = tid; i < 4 * 16 * 24; i += 256) {
        int w = i / 384, rr = (i / 24) & 15, col = 200 + (i % 24);
        int ch = (col >> 3) ^ (rr & 3);
        p_s[w][rr][(ch << 3) | (col & 7)] = 0;
    }
    for (int i = tid; i < 400; i += 256) {  // stage V^T
        int l = i >> 1, hf = i & 1;
        bfrag v = *(const bfrag*)(V + sbase + l * 16 + hf * 8);
#pragma unroll
        for (int j = 0; j < 8; j++) vt_s[hf * 8 + j][l] = (u16)v[j];
    }
    __syncthreads();

    bfrag z8 = {0, 0, 0, 0, 0, 0, 0, 0};
    for (int t = wave; t < 13; t += 4) {
        int qb = t * 16;
        int lq = qb + l16; if (lq > 199) lq = 199;   // clamp (mask kills dupes)
        bfrag aq = z8;
        if (quad < 2) aq = *(const bfrag*)(Q + sbase + lq * 16 + quad * 8);

        float s[13][4];
#pragma unroll
        for (int kt = 0; kt < 13; kt++) {
            int lk = kt * 16 + l16; if (lk > 199) lk = 199;
            bfrag bk8 = z8;
            if (quad < 2) bk8 = *(const bfrag*)(K + sbase + lk * 16 + quad * 8);
            ffrag c = {0.f, 0.f, 0.f, 0.f};
            c = mfma16(aq, bk8, c);
            float am = am_s[kt * 16 + l16];
#pragma unroll
            for (int r = 0; r < 4; r++) s[kt][r] = c[r] * 0.25f + am;
        }
        // softmax over k (row=quad*4+r spans this quad's 16 lanes)
        float mx[4], sm[4];
#pragma unroll
        for (int r = 0; r < 4; r++) {
            mx[r] = s[0][r];
#pragma unroll
            for (int kt = 1; kt < 13; kt++) mx[r] = fmaxf(mx[r], s[kt][r]);
#pragma unroll
            for (int d = 1; d < 16; d <<= 1) mx[r] = fmaxf(mx[r], __shfl_xor(mx[r], d, 64));
            sm[r] = 0.f;
        }
#pragma unroll
        for (int kt = 0; kt < 13; kt++)
#pragma unroll
            for (int r = 0; r < 4; r++) {
                float p = __expf(s[kt][r] - mx[r]);
                s[kt][r] = p; sm[r] += p;
            }
#pragma unroll
        for (int r = 0; r < 4; r++)
#pragma unroll
            for (int d = 1; d < 16; d <<= 1) sm[r] += __shfl_xor(sm[r], d, 64);
        // P (C-layout row=quad*4+r) -> LDS: chunk = (col>>3) ^ (row&3) = ^r
#pragma unroll
        for (int kt = 0; kt < 13; kt++) {
            int colb = kt * 16 + l16;
#pragma unroll
            for (int r = 0; r < 4; r++) {
                int csw = ((((colb >> 3) ^ r) << 3)) | (colb & 7);
                p_s[wave][quad * 4 + r][csw] = f2bf(s[kt][r]);
            }
        }
        // PV: [16q][224k] @ [224k][16dh]; A-row = l16 -> chunk ^= (l16&3)
        ffrag o = {0.f, 0.f, 0.f, 0.f};
#pragma unroll
        for (int kc = 0; kc < 7; kc++) {
            int ci = (kc * 4 + quad) ^ (l16 & 3);
            bfrag ap  = *(const bfrag*)&p_s[wave][l16][ci << 3];
            bfrag bv8 = *(const bfrag*)&vt_s[l16][kc * 32 + quad * 8];
            o = mfma16(ap, bv8, o);
        }
#pragma unroll
        for (int r = 0; r < 4; r++) {
            int l = qb + quad * 4 + r;
            if (l < 200)
                Q[sbase + l * 16 + l16] = f2bf(o[r] / sm[r]);  // ctx in-place
        }
    }
}

// ---------------------------------------------------------------------------
// Query pooling per batch. grid 256, block 256. f32 out.
// ---------------------------------------------------------------------------
__global__ __launch_bounds__(256) void pool_k(
    const u16* __restrict__ NO, const int* __restrict__ msk,
    const float* __restrict__ qn, float* __restrict__ out)
{
    const int b = blockIdx.x;
    const int tid = threadIdx.x;
    __shared__ float q_sh[256];
    __shared__ float p_sh[256];
    __shared__ float redm[4], reds[4];

    q_sh[tid] = qn[tid];
    __syncthreads();

    float s = -1e30f;
    if (tid < 200) {
        const u16* row = NO + (size_t)(b * 200 + tid) * 256;
        float acc = 0.f;
        for (int d0 = 0; d0 < 256; d0 += 8) {
            bfrag v = *(const bfrag*)(row + d0);
#pragma unroll
            for (int j = 0; j < 8; j++) acc += bf2f((u16)v[j]) * q_sh[d0 + j];
        }
        s = acc * 0.0625f;
        if (msk[b * 200 + tid] == 0) s = -1e9f;
    }
    float m = s;
#pragma unroll
    for (int d = 1; d < 64; d <<= 1) m = fmaxf(m, __shfl_xor(m, d, 64));
    if ((tid & 63) == 0) redm[tid >> 6] = m;
    __syncthreads();
    m = fmaxf(fmaxf(redm[0], redm[1]), fmaxf(redm[2], redm[3]));
    float e = __expf(s - m);
    float sum = e;
#pragma unroll
    for (int d = 1; d < 64; d <<= 1) sum += __shfl_xor(sum, d, 64);
    if ((tid & 63) == 0) reds[tid >> 6] = sum;
    __syncthreads();
    sum = reds[0] + reds[1] + reds[2] + reds[3];
    p_sh[tid] = e / sum;
    __syncthreads();

    float acc = 0.f;
    for (int l = 0; l < 200; l++)
        acc += p_sh[l] * bf2f(NO[(size_t)(b * 200 + l) * 256 + tid]);
    out[(size_t)b * 256 + tid] = acc;
}

// ---------------------------------------------------------------------------
extern "C" void kernel_launch(void* const* d_in, const int* in_sizes, int n_in,
                              void* d_out, int out_size, void* d_ws, size_t ws_size,
                              hipStream_t stream) {
    const float* X   = (const float*)d_in[0];
    const int*   msk = (const int*)d_in[1];
    const float* Wq  = (const float*)d_in[2];
    const float* bq  = (const float*)d_in[3];
    const float* Wk  = (const float*)d_in[4];
    const float* bk  = (const float*)d_in[5];
    const float* Wv  = (const float*)d_in[6];
    const float* bv  = (const float*)d_in[7];
    const float* Wo  = (const float*)d_in[8];
    const float* bo  = (const float*)d_in[9];
    const float* qn  = (const float*)d_in[10];
    float* out = (float*)d_out;

    // ws layout (79,167,488 B):
    //   qbuf: Q head-major -> ctx in-place     26,214,400
    //   kbuf: K head-major -> news_out l-major 26,214,400
    //   vbuf: V head-major                     26,214,400
    //   wt:   [1024][256] bf16 (Wq,Wk,Wv,Wo)^T    524,288
    char* ws = (char*)d_ws;
    u16* qbuf = (u16*)(ws);
    u16* kbuf = (u16*)(ws + 26214400);
    u16* vbuf = (u16*)(ws + 52428800);
    u16* wt   = (u16*)(ws + 78643200);

    wtrans_k<<<dim3(4, 4, 4), 256, 0, stream>>>(Wq, Wk, Wv, Wo, wt);

    gemm_k<true><<<dim3(400, 6), 256, 0, stream>>>(
        X, wt, bq, bk, bv, qbuf, kbuf, vbuf);

    attn_k<<<4096, 256, 0, stream>>>(qbuf, kbuf, vbuf, msk);

    gemm_k<false><<<dim3(400, 2), 256, 0, stream>>>(
        qbuf, wt + 196608, bo, nullptr, nullptr, kbuf, nullptr, nullptr);

    pool_k<<<256, 256, 0, stream>>>(kbuf, msk, qn, out);
}